// Round 2
// baseline (2284.192 us; speedup 1.0000x reference)
//
#include <hip/hip_runtime.h>
#include <hip/hip_bf16.h>

typedef __hip_bfloat16 bf16;

// Problem dims
#define NB 4
#define NC 256
#define NPIX 36864          // 192*192
#define NH 192
#define NW 192
#define SW 98               // db3 subband: (192+8-6)/2+1
#define SH 98
#define SUBN 9604           // SH*SW
#define ROWPL 18816         // NH*SW
#define ROWTOT 19267584     // NB*NC*ROWPL
#define PSUB 9834496        // NB*NC*SUBN
#define BROWS 24            // rows per band
#define NBANDS 8
#define BANDN 4608          // BROWS*NW

// db3: analysis correlation kernels (pre-flipped dec filters); synthesis G0S=DEC_LO, G1S=DEC_HI
__device__ __constant__ float cH0A[6] = {  0.33267055295095688f,  0.80689150931333875f,  0.45987750211933132f, -0.13501102001039084f, -0.085441273882241486f, 0.035226291882100656f };
__device__ __constant__ float cH1A[6] = {  0.035226291882100656f, 0.085441273882241486f, -0.13501102001039084f, -0.45987750211933132f,  0.80689150931333875f, -0.33267055295095688f };
__device__ __constant__ float cG0S[6] = {  0.035226291882100656f, -0.085441273882241486f, -0.13501102001039084f, 0.45987750211933132f,  0.80689150931333875f,  0.33267055295095688f };
__device__ __constant__ float cG1S[6] = { -0.33267055295095688f,  0.80689150931333875f, -0.45987750211933132f, -0.13501102001039084f,  0.085441273882241486f, 0.035226291882100656f };

// ---------------- wavelet analysis ----------------

// row DWT: x (B,C,192,192) f32 -> lo,hi (B,C,192,98) bf16 (stored in d_out region)
__global__ __launch_bounds__(256) void k_dwt_row(const float* __restrict__ x,
                                                 bf16* __restrict__ lo, bf16* __restrict__ hi) {
    int idx = blockIdx.x * 256 + threadIdx.x;
    if (idx >= ROWTOT) return;
    int wo = idx % SW;
    int rest = idx / SW;
    const float* xr = x + (size_t)rest * NW;
    int base = 2 * wo - 4;
    float la = 0.f, ha = 0.f;
#pragma unroll
    for (int t = 0; t < 6; ++t) {
        int j = base + t;
        if (j >= 0 && j < NW) {
            float v = xr[j];
            la = fmaf(v, cH0A[t], la);
            ha = fmaf(v, cH1A[t], ha);
        }
    }
    lo[idx] = __float2bfloat16(la); hi[idx] = __float2bfloat16(ha);
}

// col DWT: lo,hi -> 4 subband planes (plane-major, each B*C*98*98) bf16
__global__ __launch_bounds__(256) void k_dwt_col(const bf16* __restrict__ lo, const bf16* __restrict__ hi,
                                                 bf16* __restrict__ sub) {
    int idx = blockIdx.x * 256 + threadIdx.x;
    if (idx >= PSUB) return;
    int wo = idx % SW;
    int ho = (idx / SW) % SH;
    int bc = idx / SUBN;
    const bf16* lop = lo + (size_t)bc * ROWPL;
    const bf16* hp  = hi + (size_t)bc * ROWPL;
    int base = 2 * ho - 4;
    float ll = 0.f, lh = 0.f, hl = 0.f, hh = 0.f;
#pragma unroll
    for (int t = 0; t < 6; ++t) {
        int j = base + t;
        if (j >= 0 && j < NH) {
            float lv = __bfloat162float(lop[j * SW + wo]);
            float hv = __bfloat162float(hp[j * SW + wo]);
            ll = fmaf(lv, cH0A[t], ll); lh = fmaf(lv, cH1A[t], lh);
            hl = fmaf(hv, cH0A[t], hl); hh = fmaf(hv, cH1A[t], hh);
        }
    }
    sub[idx] = __float2bfloat16(ll);
    sub[(size_t)PSUB + idx] = __float2bfloat16(lh);
    sub[2 * (size_t)PSUB + idx] = __float2bfloat16(hl);
    sub[3 * (size_t)PSUB + idx] = __float2bfloat16(hh);
}

// ---------------- fused: dw3x3(subbands) + col-IDWT + row-IDWT -> q (f32 in d_out) + q-norm ----------------
// Tile: TW=48 x TH=32 output pixels per block, one (b,c) plane per block.
#define TTH 32
#define TTW 48
#define JH 19
#define JW 27
#define SHL 21   // JH+2 sub rows loaded
#define SWL 29   // JW+2 sub cols loaded

__global__ __launch_bounds__(256) void k_synth(const bf16* __restrict__ sub,
                                               const float* __restrict__ w5, const float* __restrict__ w7,
                                               const float* __restrict__ w9,
                                               float* __restrict__ q, float* __restrict__ qsum) {
    int w0 = blockIdx.x * TTW;
    int h0 = blockIdx.y * TTH;
    int bc = blockIdx.z;
    int c = bc % NC;
    int jh0 = h0 >> 1, jw0 = w0 >> 1;
    __shared__ float s_sub[4][SHL][SWL];
    __shared__ float s_c[4][JH][JW];
    __shared__ float s_lh[2][TTH][JW];
    __shared__ float s_w[3][9];
    __shared__ float red[4];
    int t = threadIdx.x;
    if (t < 27) {
        int f = t / 9, k = t % 9;
        const float* wsel = (f == 0) ? w5 : (f == 1 ? w7 : w9);
        s_w[f][k] = wsel[c * 9 + k];
    }
    // stage a: load sub region (zero-fill OOB = zero-pad semantics)
    const bf16* sp = sub + (size_t)bc * SUBN;
    for (int e = t; e < 4 * SHL * SWL; e += 256) {
        int pl = e / (SHL * SWL);
        int r = (e / SWL) % SHL;
        int cc = e % SWL;
        int jr = jh0 - 1 + r, jc = jw0 - 1 + cc;
        float v = 0.f;
        if (jr >= 0 && jr < SH && jc >= 0 && jc < SW)
            v = __bfloat162float(sp[(size_t)pl * PSUB + jr * SW + jc]);
        s_sub[pl][r][cc] = v;
    }
    __syncthreads();
    // stage b: 3x3 depthwise conv (pad-1) on each subband plane
    for (int e = t; e < 4 * JH * JW; e += 256) {
        int pl = e / (JH * JW);
        int r = (e / JW) % JH;
        int cc = e % JW;
        const float* wp = s_w[pl <= 1 ? 0 : pl - 1];
        float a = 0.f;
#pragma unroll
        for (int ky = 0; ky < 3; ++ky)
#pragma unroll
            for (int kx = 0; kx < 3; ++kx)
                a = fmaf(s_sub[pl][r + ky][cc + kx], wp[ky * 3 + kx], a);
        s_c[pl][r][cc] = a;
    }
    __syncthreads();
    // stage c: column synthesis (lhs_dil=2, pad=1): lo2 from (llc,lhc), hi2 from (hlc,hhc)
    for (int e = t; e < 2 * TTH * JW; e += 256) {
        int which = e / (TTH * JW);
        int hh = (e / JW) % TTH;
        int jc = e % JW;
        float a = 0.f;
#pragma unroll
        for (int th = 0; th < 6; ++th) {
            if ((hh + th + h0) & 1) {
                int jl = (hh + th - 1) >> 1;       // (h0 even) local c-row
                a = fmaf(s_c[2 * which + 0][jl][jc], cG0S[th], a);
                a = fmaf(s_c[2 * which + 1][jl][jc], cG1S[th], a);
            }
        }
        s_lh[which][hh][jc] = a;
    }
    __syncthreads();
    // stage d: row synthesis -> q, accumulate sum(q^2)
    float lsum = 0.f;
    float* qp = q + (size_t)bc * NPIX;
    for (int e = t; e < TTH * TTW; e += 256) {
        int ww = e % TTW, hh = e / TTW;
        float a = 0.f;
#pragma unroll
        for (int tw = 0; tw < 6; ++tw) {
            if ((ww + tw + w0) & 1) {
                int jl = (ww + tw - 1) >> 1;       // (w0 even) local col
                a = fmaf(s_lh[0][hh][jl], cG0S[tw], a);
                a = fmaf(s_lh[1][hh][jl], cG1S[tw], a);
            }
        }
        qp[(size_t)(h0 + hh) * NW + w0 + ww] = a;
        lsum = fmaf(a, a, lsum);
    }
#pragma unroll
    for (int off = 32; off; off >>= 1) lsum += __shfl_down(lsum, off, 64);
    if ((t & 63) == 0) red[t >> 6] = lsum;
    __syncthreads();
    if (t == 0) atomicAdd(&qsum[bc], red[0] + red[1] + red[2] + red[3]);
}

// ---------------- GEMM (1x1 convs), fp32 accum ----------------

__device__ inline float ldf(const float* p) { return *p; }
__device__ inline float ldf(const bf16* p)  { return __bfloat162float(*p); }
__device__ inline unsigned short bfbits(float f) {
    bf16 h = __float2bfloat16(f);
    return *reinterpret_cast<unsigned short*>(&h);
}
__device__ inline void stvec4(float* p, const float* a) {
    *reinterpret_cast<float4*>(p) = make_float4(a[0], a[1], a[2], a[3]);
}
__device__ inline void stvec4(bf16* p, const float* a) {
    ushort4 u; u.x = bfbits(a[0]); u.y = bfbits(a[1]); u.z = bfbits(a[2]); u.w = bfbits(a[3]);
    *reinterpret_cast<ushort4*>(p) = u;
}

// Out[b,o,n] = sum_{c<256} W[(b),o,c] * X[b,c,n].  K fixed = 256. 64x64 tile, 4x4/thread.
template <typename TIN, typename TOUT>
__global__ __launch_bounds__(256) void k_gemm2(const TIN* __restrict__ X, size_t xBatch, int xRow,
                                               const float* __restrict__ Wm, int wBatch,
                                               TOUT* __restrict__ Out, size_t oBatch, int oRow) {
    __shared__ float Xs[64][64];
    __shared__ float Ws[64][68];
    int b = blockIdx.z;
    int o0 = blockIdx.x * 64;
    int n0 = blockIdx.y * 64;
    const TIN* Xb = X + (size_t)b * xBatch;
    const float* Wb = Wm + (size_t)b * wBatch;
    TOUT* Ob = Out + (size_t)b * oBatch;
    int t = threadIdx.x;
    int to = t >> 4, tn = t & 15;
    float acc[4][4] = {};
    for (int kc = 0; kc < 256; kc += 64) {
#pragma unroll
        for (int i = 0; i < 16; ++i) {
            int e = t + 256 * i;
            int cc = e >> 6, nn = e & 63;
            Xs[cc][nn] = ldf(Xb + (size_t)(kc + cc) * xRow + n0 + nn);
        }
#pragma unroll
        for (int i = 0; i < 16; ++i) {
            int e = t + 256 * i;
            int oo = e >> 6, cc = e & 63;
            Ws[cc][oo] = Wb[(o0 + oo) * 256 + kc + cc];
        }
        __syncthreads();
#pragma unroll
        for (int c = 0; c < 64; ++c) {
            float4 xv = *reinterpret_cast<const float4*>(&Xs[c][tn * 4]);
            float4 wv = *reinterpret_cast<const float4*>(&Ws[c][to * 4]);
            float xa[4] = { xv.x, xv.y, xv.z, xv.w };
            float wa[4] = { wv.x, wv.y, wv.z, wv.w };
#pragma unroll
            for (int i = 0; i < 4; ++i)
#pragma unroll
                for (int j = 0; j < 4; ++j)
                    acc[i][j] = fmaf(wa[i], xa[j], acc[i][j]);
        }
        __syncthreads();
    }
#pragma unroll
    for (int i = 0; i < 4; ++i)
        stvec4(Ob + (size_t)(o0 + to * 4 + i) * oRow + n0 + tn * 4, acc[i]);
}

// ---------------- band depthwise 3x3 (k or v half), optional sum(val^2) per channel ----------------

__global__ __launch_bounds__(192) void k_dw_band(const bf16* __restrict__ raw, const float* __restrict__ wq,
                                                 int wofs, bf16* __restrict__ band, int r0,
                                                 float* __restrict__ ksum) {
    __shared__ float red[3];
    int bid = blockIdx.x;
    int row = bid % BROWS;
    int ch = (bid / BROWS) % 256;
    int b = bid / (BROWS * 256);
    int t = threadIdx.x;                      // w coordinate, 0..191
    int h = r0 + row;
    const bf16* ip = raw + ((size_t)b * 256 + ch) * NPIX;
    const float* wp = wq + (size_t)(wofs + ch) * 9;
    float acc = 0.f;
#pragma unroll
    for (int ky = 0; ky < 3; ++ky) {
        int y = h + ky - 1;
        if (y < 0 || y >= NH) continue;
#pragma unroll
        for (int kx = 0; kx < 3; ++kx) {
            int xw = t + kx - 1;
            if (xw < 0 || xw >= NW) continue;
            acc = fmaf(__bfloat162float(ip[y * NW + xw]), wp[ky * 3 + kx], acc);
        }
    }
    band[(((size_t)b * 256 + ch) * BROWS + row) * NW + t] = __float2bfloat16(acc);
    if (ksum != nullptr) {
        float s = acc * acc;
#pragma unroll
        for (int off = 32; off; off >>= 1) s += __shfl_down(s, off, 64);
        if ((t & 63) == 0) red[t >> 6] = s;
        __syncthreads();
        if (t == 0) atomicAdd(&ksum[b * 256 + ch], red[0] + red[1] + red[2]);
    }
}

// ---------------- Gram partials per band: q (f32) x k2band (bf16) ----------------
// grid (2 chunks of 2304 n, 32 bh). 4 groups of 64 lanes; lane owns 4x4 of the 32x32 tile.
__global__ __launch_bounds__(256) void k_gpart_band(const float* __restrict__ q, const bf16* __restrict__ kband,
                                                    float* __restrict__ gpart, int r0, int bandi) {
    int chunk = blockIdx.x;
    int bh = blockIdx.y;
    int b = bh >> 3, h = bh & 7;
    const float* qb = q + ((size_t)b * NC + h * 32) * NPIX + (size_t)r0 * NW + chunk * 2304;
    const bf16* kb = kband + ((size_t)b * 256 + h * 32) * BANDN + chunk * 2304;
    __shared__ float Qs[32][132];
    __shared__ float Ks[32][132];
    int t = threadIdx.x;
    int g = t >> 6, lane = t & 63;
    int td = lane >> 3, te = lane & 7;
    float acc[4][4] = {};
    for (int s = 0; s < 18; ++s) {
        int n0 = s * 128;
#pragma unroll
        for (int i = 0; i < 16; ++i) {
            int e = t + 256 * i;
            int d = e >> 7, nn = e & 127;
            Qs[d][nn] = qb[(size_t)d * NPIX + n0 + nn];
            Ks[d][nn] = __bfloat162float(kb[(size_t)d * BANDN + n0 + nn]);
        }
        __syncthreads();
#pragma unroll
        for (int i4 = 0; i4 < 32; i4 += 4) {
            int ii = g * 32 + i4;
            float4 qv[4], kvv[4];
#pragma unroll
            for (int x = 0; x < 4; ++x) qv[x] = *reinterpret_cast<const float4*>(&Qs[td * 4 + x][ii]);
#pragma unroll
            for (int x = 0; x < 4; ++x) kvv[x] = *reinterpret_cast<const float4*>(&Ks[te * 4 + x][ii]);
#pragma unroll
            for (int di = 0; di < 4; ++di)
#pragma unroll
                for (int ei = 0; ei < 4; ++ei)
                    acc[di][ei] += qv[di].x * kvv[ei].x + qv[di].y * kvv[ei].y
                                 + qv[di].z * kvv[ei].z + qv[di].w * kvv[ei].w;
        }
        __syncthreads();
    }
    int slot = bandi * 2 + chunk;
    float* gp = gpart + (((size_t)bh * 16 + slot) * 4 + g) * 1024;
#pragma unroll
    for (int di = 0; di < 4; ++di)
#pragma unroll
        for (int ei = 0; ei < 4; ++ei)
            gp[(td * 4 + di) * 32 + te * 4 + ei] = acc[di][ei];
}

// reduce 64 partials + normalize + temperature + row softmax
__global__ __launch_bounds__(1024) void k_attn(const float* __restrict__ gpart, const float* __restrict__ qsum,
                                               const float* __restrict__ ksum, const float* __restrict__ temp,
                                               float* __restrict__ attn) {
    int bh = blockIdx.x;
    int b = bh >> 3, h = bh & 7;
    int t = threadIdx.x;
    int d = t >> 5, e = t & 31;
    float s = 0.f;
    for (int i = 0; i < 64; ++i) s += gpart[((size_t)bh * 64 + i) * 1024 + t];
    float rq = 1.f / fmaxf(sqrtf(qsum[b * NC + h * 32 + d]), 1e-12f);
    float rk = 1.f / fmaxf(sqrtf(ksum[b * 256 + h * 32 + e]), 1e-12f);
    s *= rq * rk * temp[h];
    float m = s;
#pragma unroll
    for (int off = 16; off; off >>= 1) m = fmaxf(m, __shfl_xor(m, off, 32));
    float ex = expf(s - m);
    float sum = ex;
#pragma unroll
    for (int off = 16; off; off >>= 1) sum += __shfl_xor(sum, off, 32);
    attn[(size_t)bh * 1024 + t] = ex / sum;
}

// fold proj into attn: wf[b,o,h*32+e] = sum_d proj[o,h*32+d] * attn[b,h,d,e]
__global__ __launch_bounds__(256) void k_wfold(const float* __restrict__ proj, const float* __restrict__ attn,
                                               float* __restrict__ wf) {
    int o = blockIdx.x, b = blockIdx.y;
    int t = threadIdx.x;
    int h = t >> 5, e = t & 31;
    const float* ap = attn + (size_t)(b * 8 + h) * 1024 + e;
    const float* pp = proj + o * NC + h * 32;
    float acc = 0.f;
#pragma unroll
    for (int d = 0; d < 32; ++d) acc = fmaf(pp[d], ap[d * 32], acc);
    wf[((size_t)b * NC + o) * NC + t] = acc;
}

// ---------------- launcher ----------------

extern "C" void kernel_launch(void* const* d_in, const int* in_sizes, int n_in,
                              void* d_out, int out_size, void* d_ws, size_t ws_size,
                              hipStream_t stream) {
    (void)in_sizes; (void)n_in; (void)out_size;
    const float* x      = (const float*)d_in[0];
    const float* qkv_w  = (const float*)d_in[1];
    const float* qkv_cw = (const float*)d_in[2];
    const float* w5     = (const float*)d_in[3];
    const float* w7     = (const float*)d_in[4];
    const float* w9     = (const float*)d_in[5];
    const float* projw  = (const float*)d_in[6];
    const float* temp   = (const float*)d_in[7];

    // ws layout (bytes). raw (k/v) overlays sub (dead). Peak ~93 MiB.
    const size_t OFF_SUB   = 0;                         // 4*PSUB*2      = 78,675,968
    const size_t OFF_RAW   = 0;                         // 4*256*NPIX*2  = 75,497,472
    const size_t OFF_BAND  = 78675968;                  // 9,437,184
    const size_t OFF_GPART = OFF_BAND + 9437184;        // 8,388,608
    const size_t OFF_QSUM  = OFF_GPART + 8388608;       // 4,096
    const size_t OFF_KSUM  = OFF_QSUM + 4096;           // 4,096
    const size_t OFF_ATTN  = OFF_KSUM + 4096;           // 131,072
    const size_t OFF_WF    = OFF_ATTN + 131072;         // 1,048,576
    const size_t WS_NEED   = OFF_WF + 1048576;          // 97,689,600
    if (ws_size < WS_NEED) return;  // output stays zero -> visible failure

    char* ws = (char*)d_ws;
    bf16*  sub   = (bf16*)(ws + OFF_SUB);
    bf16*  raw   = (bf16*)(ws + OFF_RAW);
    bf16*  band  = (bf16*)(ws + OFF_BAND);
    float* gpart = (float*)(ws + OFF_GPART);
    float* qsum  = (float*)(ws + OFF_QSUM);
    float* ksum  = (float*)(ws + OFF_KSUM);
    float* attn  = (float*)(ws + OFF_ATTN);
    float* wf    = (float*)(ws + OFF_WF);

    // d_out rotates: lo|hi (bf16, 77MB) -> q (f32, 151MB) -> final output
    bf16*  lo = (bf16*)d_out;
    bf16*  hi = lo + (size_t)ROWTOT;
    float* q  = (float*)d_out;
    float* out = (float*)d_out;

    hipMemsetAsync(ws + OFF_QSUM, 0, 8192, stream);   // qsum + ksum

    // wavelet query path: x -> lo/hi -> sub -> (dw3x3 + idwt fused) -> q + qsum
    k_dwt_row<<<ROWTOT / 256, 256, 0, stream>>>(x, lo, hi);
    k_dwt_col<<<PSUB / 256, 256, 0, stream>>>(lo, hi, sub);
    k_synth<<<dim3(4, 6, NB * NC), 256, 0, stream>>>(sub, w5, w7, w9, q, qsum);

    // k path: gemm (rows 0..255) -> kraw; per band: dw3x3(+ksum) -> Gram partials vs q
    k_gemm2<float, bf16><<<dim3(4, 576, NB), 256, 0, stream>>>(
        x, (size_t)NC * NPIX, NPIX, qkv_w, 0, raw, (size_t)256 * NPIX, NPIX);
    for (int bi = 0; bi < NBANDS; ++bi) {
        int r0 = bi * BROWS;
        k_dw_band<<<NB * 256 * BROWS, 192, 0, stream>>>(raw, qkv_cw, 0, band, r0, ksum);
        k_gpart_band<<<dim3(2, 32), 256, 0, stream>>>(q, band, gpart, r0, bi);
    }

    k_attn<<<32, 1024, 0, stream>>>(gpart, qsum, ksum, temp, attn);
    k_wfold<<<dim3(256, NB), 256, 0, stream>>>(projw, attn, wf);

    // v path: gemm (rows 256..511) -> vraw; per band: dw3x3 -> out band = wf @ v2band
    k_gemm2<float, bf16><<<dim3(4, 576, NB), 256, 0, stream>>>(
        x, (size_t)NC * NPIX, NPIX, qkv_w + 65536, 0, raw, (size_t)256 * NPIX, NPIX);
    for (int bi = 0; bi < NBANDS; ++bi) {
        int r0 = bi * BROWS;
        k_dw_band<<<NB * 256 * BROWS, 192, 0, stream>>>(raw, qkv_cw, 256, band, r0, nullptr);
        k_gemm2<bf16, float><<<dim3(4, 72, NB), 256, 0, stream>>>(
            band, (size_t)256 * BANDN, BANDN, wf, 65536,
            out + (size_t)r0 * NW, (size_t)NC * NPIX, NPIX);
    }
}

// Round 3
// 912.920 us; speedup vs baseline: 2.5021x; 2.5021x over previous
//
#include <hip/hip_runtime.h>
#include <hip/hip_bf16.h>

typedef __hip_bfloat16 bf16;
typedef __attribute__((ext_vector_type(8))) short short8v;   // 8 bf16 = 4 VGPR (MFMA A/B frag)
typedef __attribute__((ext_vector_type(4))) float f32x4;     // MFMA C/D frag

// Problem dims
#define NB 4
#define NC 256
#define NPIX 36864          // 192*192
#define NH 192
#define NW 192
#define SW 98               // db3 subband: (192+8-6)/2+1
#define SH 98
#define SUBN 9604           // SH*SW
#define ROWPL 18816         // NH*SW
#define ROWTOT 19267584     // NB*NC*ROWPL
#define PSUB 9834496        // NB*NC*SUBN

// db3: analysis correlation kernels (pre-flipped dec filters); synthesis G0S=DEC_LO, G1S=DEC_HI
__device__ __constant__ float cH0A[6] = {  0.33267055295095688f,  0.80689150931333875f,  0.45987750211933132f, -0.13501102001039084f, -0.085441273882241486f, 0.035226291882100656f };
__device__ __constant__ float cH1A[6] = {  0.035226291882100656f, 0.085441273882241486f, -0.13501102001039084f, -0.45987750211933132f,  0.80689150931333875f, -0.33267055295095688f };
__device__ __constant__ float cG0S[6] = {  0.035226291882100656f, -0.085441273882241486f, -0.13501102001039084f, 0.45987750211933132f,  0.80689150931333875f,  0.33267055295095688f };
__device__ __constant__ float cG1S[6] = { -0.33267055295095688f,  0.80689150931333875f, -0.45987750211933132f, -0.13501102001039084f,  0.085441273882241486f, 0.035226291882100656f };

__device__ inline unsigned short bfbits(float f) {
    bf16 h = __float2bfloat16(f);
    return *reinterpret_cast<unsigned short*>(&h);
}

// ---------------- wavelet analysis ----------------

// row DWT: x (B,C,192,192) f32 -> lo,hi (B,C,192,98) bf16 (in d_out region)
__global__ __launch_bounds__(256) void k_dwt_row(const float* __restrict__ x,
                                                 bf16* __restrict__ lo, bf16* __restrict__ hi) {
    int idx = blockIdx.x * 256 + threadIdx.x;
    if (idx >= ROWTOT) return;
    int wo = idx % SW;
    int rest = idx / SW;
    const float* xr = x + (size_t)rest * NW;
    int base = 2 * wo - 4;
    float la = 0.f, ha = 0.f;
#pragma unroll
    for (int t = 0; t < 6; ++t) {
        int j = base + t;
        if (j >= 0 && j < NW) {
            float v = xr[j];
            la = fmaf(v, cH0A[t], la);
            ha = fmaf(v, cH1A[t], ha);
        }
    }
    lo[idx] = __float2bfloat16(la); hi[idx] = __float2bfloat16(ha);
}

// col DWT: lo,hi -> 4 subband planes (plane-major) bf16 in ws
__global__ __launch_bounds__(256) void k_dwt_col(const bf16* __restrict__ lo, const bf16* __restrict__ hi,
                                                 bf16* __restrict__ sub) {
    int idx = blockIdx.x * 256 + threadIdx.x;
    if (idx >= PSUB) return;
    int wo = idx % SW;
    int ho = (idx / SW) % SH;
    int bc = idx / SUBN;
    const bf16* lop = lo + (size_t)bc * ROWPL;
    const bf16* hp  = hi + (size_t)bc * ROWPL;
    int base = 2 * ho - 4;
    float ll = 0.f, lh = 0.f, hl = 0.f, hh = 0.f;
#pragma unroll
    for (int t = 0; t < 6; ++t) {
        int j = base + t;
        if (j >= 0 && j < NH) {
            float lv = __bfloat162float(lop[j * SW + wo]);
            float hv = __bfloat162float(hp[j * SW + wo]);
            ll = fmaf(lv, cH0A[t], ll); lh = fmaf(lv, cH1A[t], lh);
            hl = fmaf(hv, cH0A[t], hl); hh = fmaf(hv, cH1A[t], hh);
        }
    }
    sub[idx] = __float2bfloat16(ll);
    sub[(size_t)PSUB + idx] = __float2bfloat16(lh);
    sub[2 * (size_t)PSUB + idx] = __float2bfloat16(hl);
    sub[3 * (size_t)PSUB + idx] = __float2bfloat16(hh);
}

// ---------------- fused: dw3x3(subbands) + col-IDWT + row-IDWT -> qbf (bf16) + q-norm ----------------
#define TTH 32
#define TTW 48
#define JH 19
#define JW 27
#define SHL 21
#define SWL 29

__global__ __launch_bounds__(256) void k_synth(const bf16* __restrict__ sub,
                                               const float* __restrict__ w5, const float* __restrict__ w7,
                                               const float* __restrict__ w9,
                                               bf16* __restrict__ q, float* __restrict__ qsum) {
    int w0 = blockIdx.x * TTW;
    int h0 = blockIdx.y * TTH;
    int bc = blockIdx.z;
    int c = bc % NC;
    int jh0 = h0 >> 1, jw0 = w0 >> 1;
    __shared__ float s_sub[4][SHL][SWL];
    __shared__ float s_c[4][JH][JW];
    __shared__ float s_lh[2][TTH][JW];
    __shared__ float s_w[3][9];
    __shared__ float red[4];
    int t = threadIdx.x;
    if (t < 27) {
        int f = t / 9, k = t % 9;
        const float* wsel = (f == 0) ? w5 : (f == 1 ? w7 : w9);
        s_w[f][k] = wsel[c * 9 + k];
    }
    const bf16* sp = sub + (size_t)bc * SUBN;
    for (int e = t; e < 4 * SHL * SWL; e += 256) {
        int pl = e / (SHL * SWL);
        int r = (e / SWL) % SHL;
        int cc = e % SWL;
        int jr = jh0 - 1 + r, jc = jw0 - 1 + cc;
        float v = 0.f;
        if (jr >= 0 && jr < SH && jc >= 0 && jc < SW)
            v = __bfloat162float(sp[(size_t)pl * PSUB + jr * SW + jc]);
        s_sub[pl][r][cc] = v;
    }
    __syncthreads();
    for (int e = t; e < 4 * JH * JW; e += 256) {
        int pl = e / (JH * JW);
        int r = (e / JW) % JH;
        int cc = e % JW;
        const float* wp = s_w[pl <= 1 ? 0 : pl - 1];
        float a = 0.f;
#pragma unroll
        for (int ky = 0; ky < 3; ++ky)
#pragma unroll
            for (int kx = 0; kx < 3; ++kx)
                a = fmaf(s_sub[pl][r + ky][cc + kx], wp[ky * 3 + kx], a);
        s_c[pl][r][cc] = a;
    }
    __syncthreads();
    for (int e = t; e < 2 * TTH * JW; e += 256) {
        int which = e / (TTH * JW);
        int hh = (e / JW) % TTH;
        int jc = e % JW;
        float a = 0.f;
#pragma unroll
        for (int th = 0; th < 6; ++th) {
            if ((hh + th + h0) & 1) {
                int jl = (hh + th - 1) >> 1;
                a = fmaf(s_c[2 * which + 0][jl][jc], cG0S[th], a);
                a = fmaf(s_c[2 * which + 1][jl][jc], cG1S[th], a);
            }
        }
        s_lh[which][hh][jc] = a;
    }
    __syncthreads();
    float lsum = 0.f;
    bf16* qp = q + (size_t)bc * NPIX;
    for (int e = t; e < TTH * TTW; e += 256) {
        int ww = e % TTW, hh = e / TTW;
        float a = 0.f;
#pragma unroll
        for (int tw = 0; tw < 6; ++tw) {
            if ((ww + tw + w0) & 1) {
                int jl = (ww + tw - 1) >> 1;
                a = fmaf(s_lh[0][hh][jl], cG0S[tw], a);
                a = fmaf(s_lh[1][hh][jl], cG1S[tw], a);
            }
        }
        qp[(size_t)(h0 + hh) * NW + w0 + ww] = __float2bfloat16(a);
        lsum = fmaf(a, a, lsum);
    }
#pragma unroll
    for (int off = 32; off; off >>= 1) lsum += __shfl_down(lsum, off, 64);
    if ((t & 63) == 0) red[t >> 6] = lsum;
    __syncthreads();
    if (t == 0) atomicAdd(&qsum[bc], red[0] + red[1] + red[2] + red[3]);
}

// ---------------- transpose-convert: x [b][c][n] f32 -> xT [b][n][c] bf16 ----------------

__global__ __launch_bounds__(256) void k_xpose(const float* __restrict__ x, bf16* __restrict__ xT) {
    __shared__ float T[64][68];
    int nt = blockIdx.x, ct = blockIdx.y, b = blockIdx.z;
    int n0 = nt * 64, c0 = ct * 64;
    const float* xb = x + ((size_t)b * NC + c0) * NPIX + n0;
    int t = threadIdx.x;
    int tr = t >> 4, tc4 = (t & 15) * 4;
#pragma unroll
    for (int i = 0; i < 4; ++i) {
        int cc = tr + i * 16;
        float4 v = *reinterpret_cast<const float4*>(xb + (size_t)cc * NPIX + tc4);
        T[cc][tc4] = v.x; T[cc][tc4 + 1] = v.y; T[cc][tc4 + 2] = v.z; T[cc][tc4 + 3] = v.w;
    }
    __syncthreads();
    bf16* ob = xT + ((size_t)b * NPIX + n0) * NC + c0;
#pragma unroll
    for (int i = 0; i < 4; ++i) {
        int nn = tr + i * 16;
        ushort4 u;
        u.x = bfbits(T[tc4][nn]); u.y = bfbits(T[tc4 + 1][nn]);
        u.z = bfbits(T[tc4 + 2][nn]); u.w = bfbits(T[tc4 + 3][nn]);
        *reinterpret_cast<ushort4*>(ob + (size_t)nn * NC + tc4) = u;
    }
}

// convert qkv_w (512x256 f32) -> bf16
__global__ __launch_bounds__(256) void k_cvtw(const float* __restrict__ w, bf16* __restrict__ wb) {
    int idx = blockIdx.x * 256 + threadIdx.x;
    if (idx < 512 * 256) wb[idx] = __float2bfloat16(w[idx]);
}

// ---------------- MFMA GEMM: Out[b,o,n] = sum_c W[o,c] * xT[b,n,c]  (128x128 tile) ----------------
// A = W [o][c] (bf16), B = xT [n][c] (bf16, K-contiguous). Frags: lane l holds
// A[l&15][8*(l>>4)+j]; B[n=l&15][k=8*(l>>4)+j]; D: col(n)=l&15, row(o)=(l>>4)*4+r.
__global__ __launch_bounds__(256) void k_gemm_bf(const bf16* __restrict__ xT, const bf16* __restrict__ wbf,
                                                 bf16* __restrict__ outp) {
    __shared__ __align__(16) short As[128 * 64];
    __shared__ __align__(16) short Bs[128 * 64];
    int nt = blockIdx.x, ot = blockIdx.y, b = blockIdx.z;
    int n0 = nt * 128, o0 = ot * 128;
    const bf16* xb = xT + (size_t)b * NPIX * NC;
    int t = threadIdx.x;
    int wv = t >> 6, l = t & 63;
    int wr = wv >> 1, wc = wv & 1;
    f32x4 z4 = {0.f, 0.f, 0.f, 0.f};
    f32x4 acc[4][4];
#pragma unroll
    for (int m = 0; m < 4; ++m)
#pragma unroll
        for (int nf = 0; nf < 4; ++nf) acc[m][nf] = z4;
    for (int kc = 0; kc < 256; kc += 64) {
        __syncthreads();
#pragma unroll
        for (int i = 0; i < 4; ++i) {
            int blk = t + 256 * i;
            int r = blk >> 3, cb = blk & 7;
            *(short8v*)(As + blk * 8) = *(const short8v*)(wbf + (size_t)(o0 + r) * NC + kc + cb * 8);
            *(short8v*)(Bs + blk * 8) = *(const short8v*)(xb + (size_t)(n0 + r) * NC + kc + cb * 8);
        }
        __syncthreads();
#pragma unroll
        for (int kk = 0; kk < 2; ++kk) {
            short8v av[4], bv[4];
#pragma unroll
            for (int m = 0; m < 4; ++m)
                av[m] = *(const short8v*)(As + (wr * 64 + m * 16 + (l & 15)) * 64 + kk * 32 + (l >> 4) * 8);
#pragma unroll
            for (int nf = 0; nf < 4; ++nf)
                bv[nf] = *(const short8v*)(Bs + (wc * 64 + nf * 16 + (l & 15)) * 64 + kk * 32 + (l >> 4) * 8);
#pragma unroll
            for (int m = 0; m < 4; ++m)
#pragma unroll
                for (int nf = 0; nf < 4; ++nf)
                    acc[m][nf] = __builtin_amdgcn_mfma_f32_16x16x32_bf16(av[m], bv[nf], acc[m][nf], 0, 0, 0);
        }
    }
    bf16* ob = outp + (size_t)b * NC * NPIX;
#pragma unroll
    for (int m = 0; m < 4; ++m)
#pragma unroll
        for (int nf = 0; nf < 4; ++nf)
#pragma unroll
            for (int r = 0; r < 4; ++r) {
                int oo = o0 + wr * 64 + m * 16 + (l >> 4) * 4 + r;
                int nn = n0 + wc * 64 + nf * 16 + (l & 15);
                ob[(size_t)oo * NPIX + nn] = __float2bfloat16(acc[m][nf][r]);
            }
}

// ---------------- fused dw3x3 + Gram partial (MFMA) + ksum ----------------
// grid (24 row-chunks, 32 bh). Gram[d,e] += sum_n q[d,n]*dw(kraw)[e,n], K=n row-wise.
__global__ __launch_bounds__(256) void k_gram_dw(const bf16* __restrict__ qbf, const bf16* __restrict__ kraw,
                                                 const float* __restrict__ dwW,
                                                 float* __restrict__ gpart, float* __restrict__ ksum) {
    int chunk = blockIdx.x;
    int bh = blockIdx.y; int b = bh >> 3, h = bh & 7;
    const bf16* qb = qbf + ((size_t)b * NC + h * 32) * NPIX;
    const bf16* kb = kraw + ((size_t)b * NC + h * 32) * NPIX;
    __shared__ __align__(16) short Qs[32][192];
    __shared__ __align__(16) short Ks[32][192];
    __shared__ __align__(16) short Vr[32][3][200];
    __shared__ float ksh[32];
    int t = threadIdx.x;
    int wv = t >> 6, l = t & 63;
    int mh = wv >> 1, eh = wv & 1;
    int cOwn = t >> 3, sOwn = t & 7;
    float w9[9];
#pragma unroll
    for (int i = 0; i < 9; ++i) w9[i] = dwW[(h * 32 + cOwn) * 9 + i];
    if (t < 32) ksh[t] = 0.f;
    f32x4 acc = {0.f, 0.f, 0.f, 0.f};
    float k2s = 0.f;
    for (int rr = 0; rr < 8; ++rr) {
        int row = chunk * 8 + rr;
        __syncthreads();
        // stage kraw halo rows (cols -4..195 as 50 ushort4, zero-fill OOB) and q row
        for (int e = t; e < 4800; e += 256) {
            int c = e / 150; int r2 = e % 150; int dy = r2 / 50; int j = r2 % 50;
            int gr = row + dy - 1; int gc0 = -4 + 4 * j;
            ushort4 u = make_ushort4(0, 0, 0, 0);
            if (gr >= 0 && gr < NH && gc0 >= 0 && gc0 + 3 < NW)
                u = *reinterpret_cast<const ushort4*>(kb + (size_t)c * NPIX + gr * NW + gc0);
            *reinterpret_cast<ushort4*>(&Vr[c][dy][4 * j]) = u;
        }
        for (int e = t; e < 1536; e += 256) {
            int c = e / 48; int j = e % 48;
            *reinterpret_cast<ushort4*>(&Qs[c][4 * j]) =
                *reinterpret_cast<const ushort4*>(qb + (size_t)c * NPIX + row * NW + 4 * j);
        }
        __syncthreads();
        // depthwise 3x3 -> Ks (each k2 element computed exactly once; fold into ksum)
#pragma unroll
        for (int i = 0; i < 24; ++i) {
            int w = sOwn + 8 * i;
            float a = 0.f;
#pragma unroll
            for (int dy = 0; dy < 3; ++dy)
#pragma unroll
                for (int dx = 0; dx < 3; ++dx)
                    a = fmaf(__bfloat162float(*reinterpret_cast<const bf16*>(&Vr[cOwn][dy][w + dx + 3])),
                             w9[dy * 3 + dx], a);
            Ks[cOwn][w] = (short)bfbits(a);
            k2s = fmaf(a, a, k2s);
        }
        __syncthreads();
#pragma unroll
        for (int kk = 0; kk < 6; ++kk) {
            short8v av = *(const short8v*)(&Qs[mh * 16 + (l & 15)][kk * 32 + (l >> 4) * 8]);
            short8v bv = *(const short8v*)(&Ks[eh * 16 + (l & 15)][kk * 32 + (l >> 4) * 8]);
            acc = __builtin_amdgcn_mfma_f32_16x16x32_bf16(av, bv, acc, 0, 0, 0);
        }
    }
    atomicAdd(&ksh[cOwn], k2s);
    __syncthreads();
    if (t < 32) atomicAdd(&ksum[b * NC + h * 32 + t], ksh[t]);
    float* gp = gpart + ((size_t)bh * 24 + chunk) * 1024;
#pragma unroll
    for (int r = 0; r < 4; ++r) {
        int d = mh * 16 + (l >> 4) * 4 + r;
        int e = eh * 16 + (l & 15);
        gp[d * 32 + e] = acc[r];
    }
}

// reduce partials + normalize + temperature + row softmax
__global__ __launch_bounds__(1024) void k_attn(const float* __restrict__ gpart, const float* __restrict__ qsum,
                                               const float* __restrict__ ksum, const float* __restrict__ temp,
                                               float* __restrict__ attn) {
    int bh = blockIdx.x;
    int b = bh >> 3, h = bh & 7;
    int t = threadIdx.x;
    int d = t >> 5, e = t & 31;
    float s = 0.f;
    for (int i = 0; i < 24; ++i) s += gpart[((size_t)bh * 24 + i) * 1024 + t];
    float rq = 1.f / fmaxf(sqrtf(qsum[b * NC + h * 32 + d]), 1e-12f);
    float rk = 1.f / fmaxf(sqrtf(ksum[b * NC + h * 32 + e]), 1e-12f);
    s *= rq * rk * temp[h];
    float m = s;
#pragma unroll
    for (int off = 16; off; off >>= 1) m = fmaxf(m, __shfl_xor(m, off, 32));
    float ex = expf(s - m);
    float sum = ex;
#pragma unroll
    for (int off = 16; off; off >>= 1) sum += __shfl_xor(sum, off, 32);
    attn[(size_t)bh * 1024 + t] = ex / sum;
}

// fold proj into attn -> bf16: wfbf[b,o,h*32+e] = sum_d proj[o,h*32+d] * attn[b,h,d,e]
__global__ __launch_bounds__(256) void k_wfold(const float* __restrict__ proj, const float* __restrict__ attn,
                                               bf16* __restrict__ wfbf) {
    int o = blockIdx.x, b = blockIdx.y;
    int t = threadIdx.x;
    int h = t >> 5, e = t & 31;
    const float* ap = attn + (size_t)(b * 8 + h) * 1024 + e;
    const float* pp = proj + o * NC + h * 32;
    float acc = 0.f;
#pragma unroll
    for (int d = 0; d < 32; ++d) acc = fmaf(pp[d], ap[d * 32], acc);
    wfbf[((size_t)b * NC + o) * NC + t] = __float2bfloat16(acc);
}

// ---------------- final: out[b,o,seg] = sum_e wf[o,e] * dw(vraw)[e,seg]  (M=256, N=64, MFMA) ----------------
__global__ __launch_bounds__(256) void k_out_dw(const bf16* __restrict__ vraw, const bf16* __restrict__ wfbf,
                                                const float* __restrict__ dwW,   // v-half rows
                                                float* __restrict__ out) {
    int sid = blockIdx.x;            // 576 = 192 rows x 3 segs
    int b = blockIdx.y;
    int row = sid / 3, seg = sid % 3, w0 = seg * 64;
    __shared__ __align__(16) short As[256 * 64];
    __shared__ __align__(16) short Bs[64 * 64];
    __shared__ __align__(16) short Vr[64][3][72];
    const bf16* vb = vraw + (size_t)b * NC * NPIX;
    const bf16* wb = wfbf + (size_t)b * NC * NC;
    int t = threadIdx.x;
    int wv = t >> 6, l = t & 63;
    int cOwn = t & 63;
    f32x4 z4 = {0.f, 0.f, 0.f, 0.f};
    f32x4 acc[4][4];
#pragma unroll
    for (int m = 0; m < 4; ++m)
#pragma unroll
        for (int nf = 0; nf < 4; ++nf) acc[m][nf] = z4;
    for (int kc = 0; kc < 256; kc += 64) {
        float w9[9];
#pragma unroll
        for (int i = 0; i < 9; ++i) w9[i] = dwW[(kc + cOwn) * 9 + i];
        __syncthreads();
        // stage vraw halo: 64 ch x 3 rows x 18 ushort4 (cols w0-4 .. w0+67)
        for (int e = t; e < 3456; e += 256) {
            int c = e / 54; int r2 = e % 54; int dy = r2 / 18; int j = r2 % 18;
            int gr = row + dy - 1; int gc0 = w0 - 4 + 4 * j;
            ushort4 u = make_ushort4(0, 0, 0, 0);
            if (gr >= 0 && gr < NH && gc0 >= 0 && gc0 + 3 < NW)
                u = *reinterpret_cast<const ushort4*>(vb + (size_t)(kc + c) * NPIX + gr * NW + gc0);
            *reinterpret_cast<ushort4*>(&Vr[c][dy][4 * j]) = u;
        }
        // stage wf tile [256 o][64 c]
#pragma unroll
        for (int i = 0; i < 8; ++i) {
            int blk = t + 256 * i;
            int r = blk >> 3, cb = blk & 7;
            *(short8v*)(As + blk * 8) = *(const short8v*)(wb + (size_t)r * NC + kc + cb * 8);
        }
        __syncthreads();
        // depthwise -> Bs[n][c]
#pragma unroll
        for (int i = 0; i < 16; ++i) {
            int n = (t >> 6) + 4 * i;
            float a = 0.f;
#pragma unroll
            for (int dy = 0; dy < 3; ++dy)
#pragma unroll
                for (int dx = 0; dx < 3; ++dx)
                    a = fmaf(__bfloat162float(*reinterpret_cast<const bf16*>(&Vr[cOwn][dy][n + dx + 3])),
                             w9[dy * 3 + dx], a);
            Bs[n * 64 + cOwn] = (short)bfbits(a);
        }
        __syncthreads();
#pragma unroll
        for (int kk = 0; kk < 2; ++kk) {
            short8v bfr[4];
#pragma unroll
            for (int nf = 0; nf < 4; ++nf)
                bfr[nf] = *(const short8v*)(Bs + (nf * 16 + (l & 15)) * 64 + kk * 32 + (l >> 4) * 8);
#pragma unroll
            for (int m = 0; m < 4; ++m) {
                short8v av = *(const short8v*)(As + (wv * 64 + m * 16 + (l & 15)) * 64 + kk * 32 + (l >> 4) * 8);
#pragma unroll
                for (int nf = 0; nf < 4; ++nf)
                    acc[m][nf] = __builtin_amdgcn_mfma_f32_16x16x32_bf16(av, bfr[nf], acc[m][nf], 0, 0, 0);
            }
        }
    }
    float* ob = out + (size_t)b * NC * NPIX + (size_t)row * NW + w0;
#pragma unroll
    for (int m = 0; m < 4; ++m)
#pragma unroll
        for (int nf = 0; nf < 4; ++nf)
#pragma unroll
            for (int r = 0; r < 4; ++r) {
                int oo = wv * 64 + m * 16 + (l >> 4) * 4 + r;
                int nn = nf * 16 + (l & 15);
                ob[(size_t)oo * NPIX + nn] = acc[m][nf][r];
            }
}

// ---------------- launcher ----------------

extern "C" void kernel_launch(void* const* d_in, const int* in_sizes, int n_in,
                              void* d_out, int out_size, void* d_ws, size_t ws_size,
                              hipStream_t stream) {
    (void)in_sizes; (void)n_in; (void)out_size;
    const float* x      = (const float*)d_in[0];
    const float* qkv_w  = (const float*)d_in[1];
    const float* qkv_cw = (const float*)d_in[2];
    const float* w5     = (const float*)d_in[3];
    const float* w7     = (const float*)d_in[4];
    const float* w9     = (const float*)d_in[5];
    const float* projw  = (const float*)d_in[6];
    const float* temp   = (const float*)d_in[7];

    // ws layout: sub (78.7MB) then overwritten by kraw/vraw (75.5MB); smalls above.
    const size_t OFF_KV    = 0;                      // sub: 78,675,968 ; kraw/vraw: 75,497,472
    const size_t OFF_WBF   = 78675968;               // 262,144
    const size_t OFF_QSUM  = OFF_WBF + 262144;       // 4,096
    const size_t OFF_KSUM  = OFF_QSUM + 4096;        // 4,096
    const size_t OFF_GPART = OFF_KSUM + 4096;        // 3,145,728
    const size_t OFF_ATTN  = OFF_GPART + 3145728;    // 131,072
    const size_t WS_NEED   = OFF_ATTN + 131072;      // ~82.1 MB (known-safe: round1 ran with 97.7MB)
    if (ws_size < WS_NEED) return;

    char* ws = (char*)d_ws;
    bf16*  sub   = (bf16*)(ws + OFF_KV);
    bf16*  kv    = (bf16*)(ws + OFF_KV);     // kraw then vraw
    bf16*  wbf   = (bf16*)(ws + OFF_WBF);
    float* qsum  = (float*)(ws + OFF_QSUM);
    float* ksum  = (float*)(ws + OFF_KSUM);
    float* gpart = (float*)(ws + OFF_GPART);
    float* attn  = (float*)(ws + OFF_ATTN);
    bf16*  wfbf  = attn == nullptr ? nullptr : (bf16*)(ws + OFF_ATTN + 131072 - 0);  // placed after attn
    // wfbf needs 524,288 B after attn; extend WS usage (still < 97.7MB known-safe)
    wfbf = (bf16*)(ws + OFF_ATTN + 131072);

    // d_out rotation: lo|hi (bf16, 77.1MB) -> xbf [0:75.5] + qbf [75.5:151] -> final out
    bf16*  lo  = (bf16*)d_out;
    bf16*  hi  = lo + (size_t)ROWTOT;
    bf16*  xbf = (bf16*)d_out;
    bf16*  qbf = (bf16*)d_out + 37748736;
    float* out = (float*)d_out;

    hipMemsetAsync(ws + OFF_QSUM, 0, 8192, stream);   // qsum + ksum

    // wavelet analysis
    k_dwt_row<<<ROWTOT / 256, 256, 0, stream>>>(x, lo, hi);
    k_dwt_col<<<PSUB / 256, 256, 0, stream>>>(lo, hi, sub);
    // transpose-convert x (overwrites lo/hi — dead)
    k_xpose<<<dim3(576, 4, NB), 256, 0, stream>>>(x, xbf);
    k_cvtw<<<512, 256, 0, stream>>>(qkv_w, wbf);
    // synthesis -> qbf + qsum (sub consumed)
    k_synth<<<dim3(4, 6, NB * NC), 256, 0, stream>>>(sub, w5, w7, w9, qbf, qsum);

    // k path: MFMA GEMM -> kraw (overwrites sub), then fused dw+Gram
    k_gemm_bf<<<dim3(288, 2, NB), 256, 0, stream>>>(xbf, wbf, kv);
    k_gram_dw<<<dim3(24, 32), 256, 0, stream>>>(qbf, kv, qkv_cw, gpart, ksum);

    k_attn<<<32, 1024, 0, stream>>>(gpart, qsum, ksum, temp, attn);
    k_wfold<<<dim3(256, NB), 256, 0, stream>>>(projw, attn, wfbf);

    // v path: MFMA GEMM -> vraw, then fused dw + final GEMM -> out
    k_gemm_bf<<<dim3(288, 2, NB), 256, 0, stream>>>(xbf, wbf + 256 * 256, kv);
    k_out_dw<<<dim3(576, NB), 256, 0, stream>>>(kv, wfbf, qkv_cw + 256 * 9, out);
}